// Round 9
// baseline (798.465 us; speedup 1.0000x reference)
//
#include <hip/hip_runtime.h>
#include <hip/hip_bf16.h>
#include <stdint.h>

// Problem dims
#define Dd 1024
#define Ee 8
#define Ff 2816
#define Tt 8192    // B*S tokens
#define Pp 16384   // Tt * K pairs

#define BMT 128            // M tile
#define MAXT 136           // max M-tiles: Pp/128 + Ee

using bf16x8 = __attribute__((ext_vector_type(8))) short;
using f32x4  = __attribute__((ext_vector_type(4))) float;

__device__ __forceinline__ uint16_t f2bf(float f) {
    union { float f; uint32_t u; } v; v.f = f;
    return (uint16_t)((v.u + 0x7fffu + ((v.u >> 16) & 1u)) >> 16);
}
__device__ __forceinline__ uint32_t pack2(float a, float b) {
    return (uint32_t)f2bf(a) | ((uint32_t)f2bf(b) << 16);
}
__device__ __forceinline__ uint4 pack8(float4 a, float4 b) {
    uint4 r; r.x = pack2(a.x, a.y); r.y = pack2(a.z, a.w);
    r.z = pack2(b.x, b.y); r.w = pack2(b.z, b.w); return r;
}
// XOR swizzle within a 128B LDS row (G4)
__device__ __forceinline__ int swz(int row, int cb) {
    return row * 128 + (cb ^ ((row & 7) << 4));
}
__device__ __forceinline__ void gload16(const void* g, void* lds) {
    __builtin_amdgcn_global_load_lds(
        (const __attribute__((address_space(1))) uint32_t*)(uintptr_t)g,
        (__attribute__((address_space(3))) uint32_t*)(uintptr_t)lds,
        16, 0, 0);
}
__device__ __forceinline__ int xcd_swz(int b, int nwg) {
    int xcd = b & 7, pos = b >> 3;
    int q = nwg >> 3, r = nwg & 7;
    return (xcd < r ? xcd * (q + 1) : r * (q + 1) + (xcd - r) * q) + pos;
}

// ---------------- Router ----------------
__global__ __launch_bounds__(256) void router_kernel(
    const float* __restrict__ x, const float* __restrict__ gw,
    float* __restrict__ usage_bank, int* __restrict__ counts,
    int* __restrict__ tok_i, float* __restrict__ tok_w)
{
    __shared__ float us[Ee];
    int tid = threadIdx.x;
    if (tid < Ee) us[tid] = 0.f;
    __syncthreads();
    int wave = tid >> 6, lane = tid & 63;
    int t = blockIdx.x * 4 + wave;

    float xr[16];
    const float* xp = x + (size_t)t * Dd;
    #pragma unroll
    for (int j = 0; j < 16; ++j) xr[j] = xp[lane + 64 * j];

    float logits[Ee];
    #pragma unroll
    for (int e = 0; e < Ee; ++e) {
        const float* gp = gw + e * Dd;
        float s = 0.f;
        #pragma unroll
        for (int j = 0; j < 16; ++j) s += xr[j] * gp[lane + 64 * j];
        #pragma unroll
        for (int m = 1; m < 64; m <<= 1) s += __shfl_xor(s, m, 64);
        logits[e] = s;
    }
    float v1 = -1e30f, v2 = -1e30f; int i1 = 0, i2 = 0;
    #pragma unroll
    for (int e = 0; e < Ee; ++e) {
        float l = logits[e];
        if (l > v1) { v2 = v1; i2 = i1; v1 = l; i1 = e; }
        else if (l > v2) { v2 = l; i2 = e; }
    }
    float ex2 = expf(v2 - v1);
    float w1 = 1.f / (1.f + ex2);
    float w2 = ex2 * w1;
    float p[Ee]; float se = 0.f;
    #pragma unroll
    for (int e = 0; e < Ee; ++e) { p[e] = expf(logits[e] - v1); se += p[e]; }
    float inv = 1.f / se;
    if (lane == 0) {
        #pragma unroll
        for (int e = 0; e < Ee; ++e) atomicAdd(&us[e], p[e] * inv);
        atomicAdd(&counts[i1], 1);
        atomicAdd(&counts[i2], 1);
        tok_i[t * 2] = i1; tok_i[t * 2 + 1] = i2;
        tok_w[t * 2] = w1; tok_w[t * 2 + 1] = w2;
    }
    __syncthreads();
    if (tid < Ee) atomicAdd(&usage_bank[(blockIdx.x & 63) * Ee + tid], us[tid]);
}

// ---------------- conv_w1: gate/up -> interleaved bf16 W1b (output-major) ----------------
// W1b[e] rows: (f>>4)*32 + (f&15) = gate f ; +16 = up f.
// Output-sequential writes; reads are 64KB sequential bursts alternating gate/up.
// One read stream + one write stream per thread; 32 elements/thread.
__global__ __launch_bounds__(256) void conv_w1_kernel(
    const float* __restrict__ g, const float* __restrict__ u,
    uint16_t* __restrict__ dst)
{
    long long base = ((long long)blockIdx.x * 256 + threadIdx.x) * 32;
    int d = (int)(base & 1023);
    long long r = base >> 10;                    // output row in [0, Ee*5632)
    int e = (int)(r / 5632);
    int q = (int)(r - (long long)e * 5632);
    int grp = q >> 5, w = q & 31;
    const float* src = (w < 16)
        ? g + ((size_t)e * Ff + grp * 16 + w) * 1024 + d
        : u + ((size_t)e * Ff + grp * 16 + (w - 16)) * 1024 + d;
    uint16_t* dp = dst + (size_t)r * 1024 + d;
    #pragma unroll
    for (int j = 0; j < 4; ++j) {
        const float4* s = (const float4*)(src + j * 8);
        *(uint4*)(dp + j * 8) = pack8(s[0], s[1]);
    }
}

// ---------------- conv_wd: pure fp32 -> bf16 stream ----------------
__global__ __launch_bounds__(256) void conv_wd_kernel(
    const float* __restrict__ s, uint16_t* __restrict__ dst)
{
    long long i = ((long long)blockIdx.x * 256 + threadIdx.x) * 32;
    #pragma unroll
    for (int j = 0; j < 4; ++j) {
        const float4* p = (const float4*)(s + i + j * 8);
        *(uint4*)(dst + i + j * 8) = pack8(p[0], p[1]);
    }
}

// ---------------- Scan: aux + offsets + tile list ----------------
__global__ void scan_kernel(const float* __restrict__ usage_bank,
                            const int* __restrict__ counts,
                            int* __restrict__ seg_off, int* __restrict__ cursor,
                            int* __restrict__ ntiles, int* __restrict__ tile_e,
                            int* __restrict__ tile_row0, float* __restrict__ out_aux)
{
    int tid = threadIdx.x;
    __shared__ float us[Ee];
    if (tid < Ee) {
        float s = 0.f;
        for (int b = 0; b < 64; ++b) s += usage_bank[b * Ee + tid];
        us[tid] = s / (float)Tt;
    }
    __syncthreads();
    if (tid == 0) {
        float aux = 0.f;
        for (int e = 0; e < Ee; ++e) { float d = us[e] - 0.125f; aux += d * d; }
        *out_aux = aux;
        int off = 0;
        for (int e = 0; e < Ee; ++e) { seg_off[e] = off; cursor[e] = off; off += counts[e]; }
        seg_off[Ee] = off;
        int ti = 0;
        for (int e = 0; e < Ee; ++e) {
            int so = seg_off[e], cnt = counts[e];
            for (int r = 0; r < cnt; r += BMT) { tile_e[ti] = e; tile_row0[ti] = so + r; ++ti; }
        }
        *ntiles = ti;   // <= MAXT
    }
}

// ---------------- Build pair lists (+ token->slot map) ----------------
__global__ __launch_bounds__(256) void build_kernel(
    const int* __restrict__ tok_i, const float* __restrict__ tok_w,
    int* __restrict__ cursor, int* __restrict__ token_id, float* __restrict__ pair_w,
    int* __restrict__ pos)
{
    int t = blockIdx.x * 256 + threadIdx.x;
    if (t >= Tt) return;
    int i1 = tok_i[t * 2], i2 = tok_i[t * 2 + 1];
    int s1 = atomicAdd(&cursor[i1], 1);
    token_id[s1] = t; pair_w[s1] = tok_w[t * 2];     pos[t * 2] = s1;
    int s2 = atomicAdd(&cursor[i2], 1);
    token_id[s2] = t; pair_w[s2] = tok_w[t * 2 + 1]; pos[t * 2 + 1] = s2;
}

// ---------------- Gather x rows -> bf16 Xg[pair, D] ----------------
__global__ __launch_bounds__(256) void gather_kernel(
    const float* __restrict__ x, const int* __restrict__ token_id,
    uint16_t* __restrict__ Xg)
{
    int wave = threadIdx.x >> 6, lane = threadIdx.x & 63;
    int r = blockIdx.x * 4 + wave;
    if (r >= Pp) return;
    int t = token_id[r];
    const float4* src = (const float4*)(x + (size_t)t * Dd) + lane * 4;
    float4 f0 = src[0], f1 = src[1], f2 = src[2], f3 = src[3];
    uint4* dst = (uint4*)(Xg + (size_t)r * Dd) + lane * 2;
    dst[0] = pack8(f0, f1);
    dst[1] = pack8(f2, f3);
}

// ---------------- 2-wave GEMM: BM=128, BN=128, BK=64, per-wave 128x64 ----------------
// 128 threads, single-buffered 32KB LDS, 2-barrier loop, global_load_lds staging,
// 4 blocks/CU. Per-wave LDS:MFMA ratio 0.375 KB/MFMA.
// MODE 0: gemm1 (A=Xg, B=W1b interleaved; nt-major; epilogue h=silu(g)*u -> hbuf)
// MODE 1: gemm2 (A=hbuf, B=wd_b; lt-major for hbuf L2 reuse; epilogue P[pr] fp32)
// MODE 2: gemm2 atomic fallback
template<int NKT, int MODE>
__global__ __launch_bounds__(128, 2) void gemm_2w(
    const uint16_t* __restrict__ Abase, const uint16_t* __restrict__ Bbase,
    const int* __restrict__ seg_off, const int* __restrict__ tile_e,
    const int* __restrict__ tile_row0, const int* __restrict__ ntiles,
    const int* __restrict__ token_id, const float* __restrict__ pair_w,
    uint16_t* __restrict__ hbuf, float* __restrict__ Pbuf, float* __restrict__ out,
    int tile0, int Tc, int nwg)
{
    constexpr int LD = (MODE == 0) ? Dd : Ff;

    int wgid = xcd_swz(blockIdx.x, nwg);
    int nt, lt;
    if constexpr (MODE == 0) { nt = wgid / Tc; lt = wgid - nt * Tc; }     // nt-major
    else                     { lt = wgid >> 3; nt = wgid & 7; }           // lt-major
    int tidx = tile0 + lt;
    if (tidx >= *ntiles) return;
    int e = tile_e[tidx];
    int row0 = tile_row0[tidx];
    int rows = seg_off[e + 1] - row0; if (rows > BMT) rows = BMT;
    int slot = lt * BMT;

    __shared__ uint4 lds4[32768 / 16];   // A 16K | B 16K
    char* smA = (char*)lds4;
    char* smB = smA + 16384;

    int tid = threadIdx.x, lane = tid & 63, wv = tid >> 6;

    // staging: wave wv stages rows [wv*64, wv*64+64) of A and B
    int srow = lane >> 3;                        // row within 8-row group
    int csw = ((lane & 7) ^ srow) * 8;           // inverse-swizzled source col chunk
    const uint16_t* aP;
    const uint16_t* bP;
    if constexpr (MODE == 0) {
        aP = Abase + (size_t)(row0 + wv * 64 + srow) * LD + csw;
        bP = Bbase + ((size_t)e * 5632 + nt * 128 + wv * 64 + srow) * LD + csw;
    } else {
        aP = Abase + (size_t)(slot + wv * 64 + srow) * LD + csw;
        bP = Bbase + ((size_t)e * Dd + nt * 128 + wv * 64 + srow) * LD + csw;
    }
    char* aL = smA + wv * 8192;
    char* bL = smB + wv * 8192;

    f32x4 acc[8][4];
    f32x4 zero4 = {0.f, 0.f, 0.f, 0.f};
    #pragma unroll
    for (int m = 0; m < 8; ++m)
        #pragma unroll
        for (int n = 0; n < 4; ++n) acc[m][n] = zero4;

    #pragma unroll 1
    for (int kt = 0; kt < NKT; ++kt) {
        // stage tile kt: 16 gload16/thread; __syncthreads drains vmcnt+lgkm
        #pragma unroll
        for (int i = 0; i < 8; ++i) {
            gload16(aP + (size_t)(i * 8) * LD + kt * 64, aL + i * 1024);
            gload16(bP + (size_t)(i * 8) * LD + kt * 64, bL + i * 1024);
        }
        __syncthreads();
        #pragma unroll
        for (int kk = 0; kk < 2; ++kk) {
            int cb = kk * 64 + ((lane >> 4) << 4);
            bf16x8 a[8], b[4];
            #pragma unroll
            for (int m = 0; m < 8; ++m)
                a[m] = *(const bf16x8*)(smA + swz(m * 16 + (lane & 15), cb));
            #pragma unroll
            for (int n = 0; n < 4; ++n)
                b[n] = *(const bf16x8*)(smB + swz(wv * 64 + n * 16 + (lane & 15), cb));
            #pragma unroll
            for (int m = 0; m < 8; ++m)
                #pragma unroll
                for (int n = 0; n < 4; ++n)
                    acc[m][n] = __builtin_amdgcn_mfma_f32_16x16x32_bf16(a[m], b[n], acc[m][n], 0, 0, 0);
        }
        __syncthreads();   // all waves done reading before next stage overwrites
    }

    if constexpr (MODE == 0) {
        // interleaved n-frags: (0,1)=(g,u) at f0, (2,3)=(g,u) at f0+16
        int hc = nt * 64 + wv * 32 + (lane & 15);
        #pragma unroll
        for (int m = 0; m < 8; ++m) {
            #pragma unroll
            for (int g = 0; g < 4; ++g) {
                int rr = m * 16 + (lane >> 4) * 4 + g;
                if (rr < rows) {
                    uint16_t* hp = hbuf + (size_t)(slot + rr) * Ff + hc;
                    float g0 = acc[m][0][g], u0 = acc[m][1][g];
                    hp[0]  = f2bf(g0 * u0 / (1.f + expf(-g0)));
                    float g1 = acc[m][2][g], u1 = acc[m][3][g];
                    hp[16] = f2bf(g1 * u1 / (1.f + expf(-g1)));
                }
            }
        }
    } else if constexpr (MODE == 1) {
        int col = nt * 128 + wv * 64 + (lane & 15);
        #pragma unroll
        for (int m = 0; m < 8; ++m) {
            #pragma unroll
            for (int g = 0; g < 4; ++g) {
                int rr = m * 16 + (lane >> 4) * 4 + g;
                if (rr < rows) {
                    float* pp = Pbuf + (size_t)(row0 + rr) * Dd + col;
                    pp[0]  = acc[m][0][g];
                    pp[16] = acc[m][1][g];
                    pp[32] = acc[m][2][g];
                    pp[48] = acc[m][3][g];
                }
            }
        }
    } else {
        int col = nt * 128 + wv * 64 + (lane & 15);
        #pragma unroll
        for (int m = 0; m < 8; ++m) {
            #pragma unroll
            for (int g = 0; g < 4; ++g) {
                int rr = m * 16 + (lane >> 4) * 4 + g;
                if (rr < rows) {
                    int pr = row0 + rr;
                    int tok = token_id[pr];
                    float w = pair_w[pr];
                    float* op = out + (size_t)tok * Dd + col;
                    atomicAdd(op + 0,  w * acc[m][0][g]);
                    atomicAdd(op + 16, w * acc[m][1][g]);
                    atomicAdd(op + 32, w * acc[m][2][g]);
                    atomicAdd(op + 48, w * acc[m][3][g]);
                }
            }
        }
    }
}

// ---------------- Combine: out[t] = w1*P[s1] + w2*P[s2] ----------------
__global__ __launch_bounds__(256) void combine_kernel(
    const float* __restrict__ P, const int* __restrict__ pos,
    const float* __restrict__ tok_w, float* __restrict__ out)
{
    int t = blockIdx.x;
    int d = threadIdx.x * 4;
    int s1 = pos[t * 2], s2 = pos[t * 2 + 1];
    float w1 = tok_w[t * 2], w2 = tok_w[t * 2 + 1];
    float4 a = *(const float4*)(P + (size_t)s1 * Dd + d);
    float4 b = *(const float4*)(P + (size_t)s2 * Dd + d);
    float4 o;
    o.x = w1 * a.x + w2 * b.x; o.y = w1 * a.y + w2 * b.y;
    o.z = w1 * a.z + w2 * b.z; o.w = w1 * a.w + w2 * b.w;
    *(float4*)(out + (size_t)t * Dd + d) = o;
}

// ---------------- Host launch ----------------
extern "C" void kernel_launch(void* const* d_in, const int* in_sizes, int n_in,
                              void* d_out, int out_size, void* d_ws, size_t ws_size,
                              hipStream_t stream)
{
    const float* x     = (const float*)d_in[0];
    const float* gw    = (const float*)d_in[1];
    const float* wgate = (const float*)d_in[2];
    const float* wup   = (const float*)d_in[3];
    const float* wdown = (const float*)d_in[4];
    float* out = (float*)d_out;

    char* ws = (char*)d_ws;
    float* usage_bank = (float*)(ws);
    int*   counts     = (int*)(ws + 2048);
    int*   seg_off    = (int*)(ws + 2112);
    int*   cursor     = (int*)(ws + 2176);
    int*   ntiles     = (int*)(ws + 2240);
    int*   tile_e     = (int*)(ws + 4096);
    int*   tile_row0  = (int*)(ws + 5120);
    int*   tok_i      = (int*)(ws + 8192);
    float* tok_w      = (float*)(ws + 73728);
    int*   token_id   = (int*)(ws + 139264);
    float* pair_w     = (float*)(ws + 204800);
    int*   pos        = (int*)(ws + 270336);
    const size_t CTRL  = 335872;
    const size_t TILEB = (size_t)BMT * Ff * 2;          // 720,896 B per h-tile
    const size_t XgB   = (size_t)(Pp + BMT) * Dd * 2;   // 33.8 MB (padded)
    const size_t W1B   = 2ull * Ee * Ff * Dd * 2;       // 92.3 MB interleaved gate/up
    const size_t WDB   = (size_t)Ee * Dd * Ff * 2;      // 46.1 MB
    const size_t PB    = (size_t)Pp * Dd * 4;           // 67.1 MB fp32 per-pair rows

    if (ws_size >= 4096) hipMemsetAsync(ws, 0, 4096, stream);
    size_t fixed = CTRL + XgB + W1B + WDB;
    if (ws_size < fixed + TILEB) {   // cannot run the fast path; fail gracefully (no OOB)
        hipMemsetAsync(d_out, 0, (size_t)out_size * 4, stream);
        return;
    }

    uint16_t* Xg   = (uint16_t*)(ws + CTRL);
    uint16_t* W1b  = (uint16_t*)(ws + CTRL + XgB);
    uint16_t* wd_b = (uint16_t*)(ws + CTRL + XgB + W1B);
    size_t rem = ws_size - fixed;

    router_kernel<<<Tt / 4, 256, 0, stream>>>(x, gw, usage_bank, counts, tok_i, tok_w);
    scan_kernel<<<1, 64, 0, stream>>>(usage_bank, counts, seg_off, cursor,
                                      ntiles, tile_e, tile_row0, out + (out_size - 1));
    build_kernel<<<Tt / 256, 256, 0, stream>>>(tok_i, tok_w, cursor, token_id, pair_w, pos);
    gather_kernel<<<Pp / 4, 256, 0, stream>>>(x, token_id, Xg);
    // streaming weight conversions (single read stream + single write stream each)
    conv_w1_kernel<<<5632, 256, 0, stream>>>(wgate, wup, W1b);   // 45056 rows * 1024 / 32 / 256
    conv_wd_kernel<<<2816, 256, 0, stream>>>(wdown, wd_b);       // 23068672 / 32 / 256

    // choose P-buffer mode (store + combine) vs atomic mode
    int TcP = (rem > PB) ? (int)((rem - PB) / TILEB) : 0;
    if (TcP > MAXT) TcP = MAXT;
    bool useP = (TcP >= 24);
    float* Pbuf = nullptr;
    uint16_t* hbuf;
    int Tc;
    if (useP) {
        Pbuf = (float*)(ws + fixed);
        hbuf = (uint16_t*)(ws + fixed + PB);
        Tc = TcP;
    } else {
        hbuf = (uint16_t*)(ws + fixed);
        Tc = (int)(rem / TILEB);
        if (Tc > MAXT) Tc = MAXT;
        hipMemsetAsync(d_out, 0, (size_t)(out_size - 1) * 4, stream);  // atomics need zeroed out
    }
    int nchunks = (MAXT + Tc - 1) / Tc;
    Tc = (MAXT + nchunks - 1) / nchunks;   // even split

    int nwg1 = Tc * 44;   // 5632/128 interleaved n-tiles
    int nwg2 = Tc * 8;    // 1024/128 n-tiles
    for (int c = 0; c < nchunks; ++c) {
        int tile0 = c * Tc;
        gemm_2w<16, 0><<<nwg1, 128, 0, stream>>>(
            Xg, W1b, seg_off, tile_e, tile_row0, ntiles, token_id, pair_w,
            hbuf, Pbuf, out, tile0, Tc, nwg1);
        if (useP) {
            gemm_2w<44, 1><<<nwg2, 128, 0, stream>>>(
                hbuf, wd_b, seg_off, tile_e, tile_row0, ntiles, token_id, pair_w,
                hbuf, Pbuf, out, tile0, Tc, nwg2);
        } else {
            gemm_2w<44, 2><<<nwg2, 128, 0, stream>>>(
                hbuf, wd_b, seg_off, tile_e, tile_row0, ntiles, token_id, pair_w,
                hbuf, Pbuf, out, tile0, Tc, nwg2);
        }
    }
    if (useP)
        combine_kernel<<<Tt, 256, 0, stream>>>(Pbuf, pos, tok_w, out);
}

// Round 10
// 759.939 us; speedup vs baseline: 1.0507x; 1.0507x over previous
//
#include <hip/hip_runtime.h>
#include <hip/hip_bf16.h>
#include <stdint.h>

// Problem dims
#define Dd 1024
#define Ee 8
#define Ff 2816
#define Tt 8192    // B*S tokens
#define Pp 16384   // Tt * K pairs

#define BMT 128            // M tile
#define MAXT 136           // max M-tiles: Pp/128 + Ee

using bf16x8 = __attribute__((ext_vector_type(8))) short;
using f32x4  = __attribute__((ext_vector_type(4))) float;

__device__ __forceinline__ uint16_t f2bf(float f) {
    union { float f; uint32_t u; } v; v.f = f;
    return (uint16_t)((v.u + 0x7fffu + ((v.u >> 16) & 1u)) >> 16);
}
__device__ __forceinline__ uint32_t pack2(float a, float b) {
    return (uint32_t)f2bf(a) | ((uint32_t)f2bf(b) << 16);
}
__device__ __forceinline__ uint4 pack8(float4 a, float4 b) {
    uint4 r; r.x = pack2(a.x, a.y); r.y = pack2(a.z, a.w);
    r.z = pack2(b.x, b.y); r.w = pack2(b.z, b.w); return r;
}
// XOR swizzle within a 128B LDS row (G4)
__device__ __forceinline__ int swz(int row, int cb) {
    return row * 128 + (cb ^ ((row & 7) << 4));
}
__device__ __forceinline__ void gload16(const void* g, void* lds) {
    __builtin_amdgcn_global_load_lds(
        (const __attribute__((address_space(1))) uint32_t*)(uintptr_t)g,
        (__attribute__((address_space(3))) uint32_t*)(uintptr_t)lds,
        16, 0, 0);
}
__device__ __forceinline__ int xcd_swz(int b, int nwg) {
    int xcd = b & 7, pos = b >> 3;
    int q = nwg >> 3, r = nwg & 7;
    return (xcd < r ? xcd * (q + 1) : r * (q + 1) + (xcd - r) * q) + pos;
}

// ---------------- Router ----------------
__global__ __launch_bounds__(256) void router_kernel(
    const float* __restrict__ x, const float* __restrict__ gw,
    float* __restrict__ usage_bank, int* __restrict__ counts,
    int* __restrict__ tok_i, float* __restrict__ tok_w)
{
    __shared__ float us[Ee];
    int tid = threadIdx.x;
    if (tid < Ee) us[tid] = 0.f;
    __syncthreads();
    int wave = tid >> 6, lane = tid & 63;
    int t = blockIdx.x * 4 + wave;

    float xr[16];
    const float* xp = x + (size_t)t * Dd;
    #pragma unroll
    for (int j = 0; j < 16; ++j) xr[j] = xp[lane + 64 * j];

    float logits[Ee];
    #pragma unroll
    for (int e = 0; e < Ee; ++e) {
        const float* gp = gw + e * Dd;
        float s = 0.f;
        #pragma unroll
        for (int j = 0; j < 16; ++j) s += xr[j] * gp[lane + 64 * j];
        #pragma unroll
        for (int m = 1; m < 64; m <<= 1) s += __shfl_xor(s, m, 64);
        logits[e] = s;
    }
    float v1 = -1e30f, v2 = -1e30f; int i1 = 0, i2 = 0;
    #pragma unroll
    for (int e = 0; e < Ee; ++e) {
        float l = logits[e];
        if (l > v1) { v2 = v1; i2 = i1; v1 = l; i1 = e; }
        else if (l > v2) { v2 = l; i2 = e; }
    }
    float ex2 = expf(v2 - v1);
    float w1 = 1.f / (1.f + ex2);
    float w2 = ex2 * w1;
    float p[Ee]; float se = 0.f;
    #pragma unroll
    for (int e = 0; e < Ee; ++e) { p[e] = expf(logits[e] - v1); se += p[e]; }
    float inv = 1.f / se;
    if (lane == 0) {
        #pragma unroll
        for (int e = 0; e < Ee; ++e) atomicAdd(&us[e], p[e] * inv);
        atomicAdd(&counts[i1], 1);
        atomicAdd(&counts[i2], 1);
        tok_i[t * 2] = i1; tok_i[t * 2 + 1] = i2;
        tok_w[t * 2] = w1; tok_w[t * 2 + 1] = w2;
    }
    __syncthreads();
    if (tid < Ee) atomicAdd(&usage_bank[(blockIdx.x & 63) * Ee + tid], us[tid]);
}

// ---------------- Streaming weight conversions (one read + one write stream each) ----
// 8 elems/thread, lane-contiguous: each load instruction's lanes cover a
// contiguous 2KB span (full coalescing, G2).
// W1b[e] rows: (f>>4)*32 + (f&15) = gate f ; +16 = up f.
__global__ __launch_bounds__(256) void conv_g_kernel(
    const float* __restrict__ g, uint16_t* __restrict__ w1b)
{
    long long i = ((long long)blockIdx.x * 256 + threadIdx.x) * 8;
    int d = (int)(i & (Dd - 1));
    long long row = i >> 10;            // e*Ff + f
    int e = (int)(row / Ff), f = (int)(row - (long long)e * Ff);
    size_t rg = (size_t)e * 5632 + (size_t)(f >> 4) * 32 + (f & 15);
    const float4* s = (const float4*)(g + i);
    *(uint4*)(w1b + rg * 1024 + d) = pack8(s[0], s[1]);
}
__global__ __launch_bounds__(256) void conv_u_kernel(
    const float* __restrict__ u, uint16_t* __restrict__ w1b)
{
    long long i = ((long long)blockIdx.x * 256 + threadIdx.x) * 8;
    int d = (int)(i & (Dd - 1));
    long long row = i >> 10;
    int e = (int)(row / Ff), f = (int)(row - (long long)e * Ff);
    size_t rg = (size_t)e * 5632 + (size_t)(f >> 4) * 32 + (f & 15) + 16;
    const float4* s = (const float4*)(u + i);
    *(uint4*)(w1b + rg * 1024 + d) = pack8(s[0], s[1]);
}
__global__ __launch_bounds__(256) void conv_wd_kernel(
    const float* __restrict__ s, uint16_t* __restrict__ dst)
{
    long long i = ((long long)blockIdx.x * 256 + threadIdx.x) * 8;
    const float4* p = (const float4*)(s + i);
    *(uint4*)(dst + i) = pack8(p[0], p[1]);
}

// ---------------- Scan: aux + offsets + tile list ----------------
__global__ void scan_kernel(const float* __restrict__ usage_bank,
                            const int* __restrict__ counts,
                            int* __restrict__ seg_off, int* __restrict__ cursor,
                            int* __restrict__ ntiles, int* __restrict__ tile_e,
                            int* __restrict__ tile_row0, float* __restrict__ out_aux)
{
    int tid = threadIdx.x;
    __shared__ float us[Ee];
    if (tid < Ee) {
        float s = 0.f;
        for (int b = 0; b < 64; ++b) s += usage_bank[b * Ee + tid];
        us[tid] = s / (float)Tt;
    }
    __syncthreads();
    if (tid == 0) {
        float aux = 0.f;
        for (int e = 0; e < Ee; ++e) { float d = us[e] - 0.125f; aux += d * d; }
        *out_aux = aux;
        int off = 0;
        for (int e = 0; e < Ee; ++e) { seg_off[e] = off; cursor[e] = off; off += counts[e]; }
        seg_off[Ee] = off;
        int ti = 0;
        for (int e = 0; e < Ee; ++e) {
            int so = seg_off[e], cnt = counts[e];
            for (int r = 0; r < cnt; r += BMT) { tile_e[ti] = e; tile_row0[ti] = so + r; ++ti; }
        }
        *ntiles = ti;   // <= MAXT
    }
}

// ---------------- Build pair lists (+ token->slot map) ----------------
__global__ __launch_bounds__(256) void build_kernel(
    const int* __restrict__ tok_i, const float* __restrict__ tok_w,
    int* __restrict__ cursor, int* __restrict__ token_id, float* __restrict__ pair_w,
    int* __restrict__ pos)
{
    int t = blockIdx.x * 256 + threadIdx.x;
    if (t >= Tt) return;
    int i1 = tok_i[t * 2], i2 = tok_i[t * 2 + 1];
    int s1 = atomicAdd(&cursor[i1], 1);
    token_id[s1] = t; pair_w[s1] = tok_w[t * 2];     pos[t * 2] = s1;
    int s2 = atomicAdd(&cursor[i2], 1);
    token_id[s2] = t; pair_w[s2] = tok_w[t * 2 + 1]; pos[t * 2 + 1] = s2;
}

// ---------------- Gather x rows -> bf16 Xg[pair, D] ----------------
__global__ __launch_bounds__(256) void gather_kernel(
    const float* __restrict__ x, const int* __restrict__ token_id,
    uint16_t* __restrict__ Xg)
{
    int wave = threadIdx.x >> 6, lane = threadIdx.x & 63;
    int r = blockIdx.x * 4 + wave;
    if (r >= Pp) return;
    int t = token_id[r];
    const float4* src = (const float4*)(x + (size_t)t * Dd) + lane * 4;
    float4 f0 = src[0], f1 = src[1], f2 = src[2], f3 = src[3];
    uint4* dst = (uint4*)(Xg + (size_t)r * Dd) + lane * 2;
    dst[0] = pack8(f0, f1);
    dst[1] = pack8(f2, f3);
}

// ---------------- m97-style GEMM: BM=128, BN=128, BK=64, 4 waves ----------------
// Single-buffered LDS (32 KB), 2-barrier loop, global_load_lds staging,
// 3 blocks/CU co-residency provides the implicit pipeline (m114).
// MODE 0: gemm1 (A=Xg, B=W1b interleaved; epilogue h=silu(g)*u -> hbuf bf16)
// MODE 1: gemm2 (A=hbuf, B=wd_b; epilogue P[pr] fp32 store)
// MODE 2: gemm2 atomic (epilogue atomicAdd into out)
template<int NKT, int MODE>
__global__ __launch_bounds__(256, 3) void gemm_m97(
    const uint16_t* __restrict__ Abase, const uint16_t* __restrict__ Bbase,
    const int* __restrict__ seg_off, const int* __restrict__ tile_e,
    const int* __restrict__ tile_row0, const int* __restrict__ ntiles,
    const int* __restrict__ token_id, const float* __restrict__ pair_w,
    uint16_t* __restrict__ hbuf, float* __restrict__ Pbuf, float* __restrict__ out,
    int tile0, int Tc, int nwg)
{
    constexpr int LD = (MODE == 0) ? Dd : Ff;

    int wgid = xcd_swz(blockIdx.x, nwg);
    int nt = wgid / Tc, lt = wgid - nt * Tc;
    int tidx = tile0 + lt;
    if (tidx >= *ntiles) return;
    int e = tile_e[tidx];
    int row0 = tile_row0[tidx];
    int rows = seg_off[e + 1] - row0; if (rows > BMT) rows = BMT;
    int slot = lt * BMT;

    __shared__ uint4 lds4[32768 / 16];   // A 16K | B 16K
    char* smA = (char*)lds4;
    char* smB = smA + 16384;

    int tid = threadIdx.x, lane = tid & 63, wv = tid >> 6;
    int wr = wv >> 1, wc = wv & 1;

    // staging sources: per-lane inverse-swizzled (rule #21: LDS dest linear)
    int srow = wv * 32 + (lane >> 3);            // wave stages rows [wv*32, wv*32+32)
    int csw = ((lane & 7) ^ (lane >> 3)) * 8;    // source col chunk (elements)
    const uint16_t* aP;
    const uint16_t* bP;
    if constexpr (MODE == 0) {
        aP = Abase + (size_t)(row0 + srow) * LD + csw;
        bP = Bbase + ((size_t)e * 5632 + nt * 128 + srow) * LD + csw;
    } else {
        aP = Abase + (size_t)(slot + srow) * LD + csw;
        bP = Bbase + ((size_t)e * Dd + nt * 128 + srow) * LD + csw;
    }
    char* aL = smA + wv * 4096;
    char* bL = smB + wv * 4096;

    f32x4 acc[4][4];
    f32x4 zero4 = {0.f, 0.f, 0.f, 0.f};
    #pragma unroll
    for (int m = 0; m < 4; ++m)
        #pragma unroll
        for (int n = 0; n < 4; ++n) acc[m][n] = zero4;

    #pragma unroll 1
    for (int kt = 0; kt < NKT; ++kt) {
        // stage tile kt (8 gload16/wave); __syncthreads drains vmcnt+lgkm
        #pragma unroll
        for (int i = 0; i < 4; ++i) {
            gload16(aP + (size_t)(i * 8) * LD + kt * 64, aL + i * 1024);
            gload16(bP + (size_t)(i * 8) * LD + kt * 64, bL + i * 1024);
        }
        __syncthreads();
        #pragma unroll
        for (int kk = 0; kk < 2; ++kk) {
            int cb = kk * 64 + ((lane >> 4) << 4);
            bf16x8 a[4], b[4];
            #pragma unroll
            for (int m = 0; m < 4; ++m)
                a[m] = *(const bf16x8*)(smA + swz(wr * 64 + m * 16 + (lane & 15), cb));
            #pragma unroll
            for (int n = 0; n < 4; ++n)
                b[n] = *(const bf16x8*)(smB + swz(wc * 64 + n * 16 + (lane & 15), cb));
            #pragma unroll
            for (int m = 0; m < 4; ++m)
                #pragma unroll
                for (int n = 0; n < 4; ++n)
                    acc[m][n] = __builtin_amdgcn_mfma_f32_16x16x32_bf16(a[m], b[n], acc[m][n], 0, 0, 0);
        }
        __syncthreads();   // all waves done reading before next stage overwrites
    }

    if constexpr (MODE == 0) {
        // interleaved n-frags: (0,1)=(g,u) at f0, (2,3)=(g,u) at f0+16
        int hc = nt * 64 + wc * 32 + (lane & 15);
        #pragma unroll
        for (int m = 0; m < 4; ++m) {
            #pragma unroll
            for (int g = 0; g < 4; ++g) {
                int rr = wr * 64 + m * 16 + (lane >> 4) * 4 + g;
                if (rr < rows) {
                    uint16_t* hp = hbuf + (size_t)(slot + rr) * Ff + hc;
                    float g0 = acc[m][0][g], u0 = acc[m][1][g];
                    hp[0]  = f2bf(g0 * u0 / (1.f + expf(-g0)));
                    float g1 = acc[m][2][g], u1 = acc[m][3][g];
                    hp[16] = f2bf(g1 * u1 / (1.f + expf(-g1)));
                }
            }
        }
    } else if constexpr (MODE == 1) {
        int col = nt * 128 + wc * 64 + (lane & 15);
        #pragma unroll
        for (int m = 0; m < 4; ++m) {
            #pragma unroll
            for (int g = 0; g < 4; ++g) {
                int rr = wr * 64 + m * 16 + (lane >> 4) * 4 + g;
                if (rr < rows) {
                    float* pp = Pbuf + (size_t)(row0 + rr) * Dd + col;
                    pp[0]  = acc[m][0][g];
                    pp[16] = acc[m][1][g];
                    pp[32] = acc[m][2][g];
                    pp[48] = acc[m][3][g];
                }
            }
        }
    } else {
        int col = nt * 128 + wc * 64 + (lane & 15);
        #pragma unroll
        for (int m = 0; m < 4; ++m) {
            #pragma unroll
            for (int g = 0; g < 4; ++g) {
                int rr = wr * 64 + m * 16 + (lane >> 4) * 4 + g;
                if (rr < rows) {
                    int pr = row0 + rr;
                    int tok = token_id[pr];
                    float w = pair_w[pr];
                    float* op = out + (size_t)tok * Dd + col;
                    atomicAdd(op + 0,  w * acc[m][0][g]);
                    atomicAdd(op + 16, w * acc[m][1][g]);
                    atomicAdd(op + 32, w * acc[m][2][g]);
                    atomicAdd(op + 48, w * acc[m][3][g]);
                }
            }
        }
    }
}

// ---------------- Combine: out[t] = w1*P[s1] + w2*P[s2] ----------------
__global__ __launch_bounds__(256) void combine_kernel(
    const float* __restrict__ P, const int* __restrict__ pos,
    const float* __restrict__ tok_w, float* __restrict__ out)
{
    int t = blockIdx.x;
    int d = threadIdx.x * 4;
    int s1 = pos[t * 2], s2 = pos[t * 2 + 1];
    float w1 = tok_w[t * 2], w2 = tok_w[t * 2 + 1];
    float4 a = *(const float4*)(P + (size_t)s1 * Dd + d);
    float4 b = *(const float4*)(P + (size_t)s2 * Dd + d);
    float4 o;
    o.x = w1 * a.x + w2 * b.x; o.y = w1 * a.y + w2 * b.y;
    o.z = w1 * a.z + w2 * b.z; o.w = w1 * a.w + w2 * b.w;
    *(float4*)(out + (size_t)t * Dd + d) = o;
}

// ---------------- Host launch ----------------
extern "C" void kernel_launch(void* const* d_in, const int* in_sizes, int n_in,
                              void* d_out, int out_size, void* d_ws, size_t ws_size,
                              hipStream_t stream)
{
    const float* x     = (const float*)d_in[0];
    const float* gw    = (const float*)d_in[1];
    const float* wgate = (const float*)d_in[2];
    const float* wup   = (const float*)d_in[3];
    const float* wdown = (const float*)d_in[4];
    float* out = (float*)d_out;

    char* ws = (char*)d_ws;
    float* usage_bank = (float*)(ws);
    int*   counts     = (int*)(ws + 2048);
    int*   seg_off    = (int*)(ws + 2112);
    int*   cursor     = (int*)(ws + 2176);
    int*   ntiles     = (int*)(ws + 2240);
    int*   tile_e     = (int*)(ws + 4096);
    int*   tile_row0  = (int*)(ws + 5120);
    int*   tok_i      = (int*)(ws + 8192);
    float* tok_w      = (float*)(ws + 73728);
    int*   token_id   = (int*)(ws + 139264);
    float* pair_w     = (float*)(ws + 204800);
    int*   pos        = (int*)(ws + 270336);
    const size_t CTRL  = 335872;
    const size_t TILEB = (size_t)BMT * Ff * 2;          // 720,896 B per h-tile
    const size_t XgB   = (size_t)(Pp + BMT) * Dd * 2;   // 33.8 MB (padded)
    const size_t W1B   = 2ull * Ee * Ff * Dd * 2;       // 92.3 MB interleaved gate/up
    const size_t WDB   = (size_t)Ee * Dd * Ff * 2;      // 46.1 MB
    const size_t PB    = (size_t)Pp * Dd * 4;           // 67.1 MB fp32 per-pair rows

    if (ws_size >= 4096) hipMemsetAsync(ws, 0, 4096, stream);
    size_t fixed = CTRL + XgB + W1B + WDB;
    if (ws_size < fixed + TILEB) {   // cannot run the fast path; fail gracefully (no OOB)
        hipMemsetAsync(d_out, 0, (size_t)out_size * 4, stream);
        return;
    }

    uint16_t* Xg   = (uint16_t*)(ws + CTRL);
    uint16_t* W1b  = (uint16_t*)(ws + CTRL + XgB);
    uint16_t* wd_b = (uint16_t*)(ws + CTRL + XgB + W1B);
    size_t rem = ws_size - fixed;

    router_kernel<<<Tt / 4, 256, 0, stream>>>(x, gw, usage_bank, counts, tok_i, tok_w);
    scan_kernel<<<1, 64, 0, stream>>>(usage_bank, counts, seg_off, cursor,
                                      ntiles, tile_e, tile_row0, out + (out_size - 1));
    build_kernel<<<Tt / 256, 256, 0, stream>>>(tok_i, tok_w, cursor, token_id, pair_w, pos);
    gather_kernel<<<Pp / 4, 256, 0, stream>>>(x, token_id, Xg);
    // single-stream weight conversions (lane-contiguous, 8 elems/thread)
    conv_g_kernel<<<11264, 256, 0, stream>>>(wgate, W1b);
    conv_u_kernel<<<11264, 256, 0, stream>>>(wup, W1b);
    conv_wd_kernel<<<11264, 256, 0, stream>>>(wdown, wd_b);

    // choose P-buffer mode (store + combine) vs atomic mode
    int TcP = (rem > PB) ? (int)((rem - PB) / TILEB) : 0;
    if (TcP > MAXT) TcP = MAXT;
    bool useP = (TcP >= 24);
    float* Pbuf = nullptr;
    uint16_t* hbuf;
    int Tc;
    if (useP) {
        Pbuf = (float*)(ws + fixed);
        hbuf = (uint16_t*)(ws + fixed + PB);
        Tc = TcP;
    } else {
        hbuf = (uint16_t*)(ws + fixed);
        Tc = (int)(rem / TILEB);
        if (Tc > MAXT) Tc = MAXT;
        hipMemsetAsync(d_out, 0, (size_t)(out_size - 1) * 4, stream);  // atomics need zeroed out
    }
    int nchunks = (MAXT + Tc - 1) / Tc;
    Tc = (MAXT + nchunks - 1) / nchunks;   // even split

    int nwg1 = Tc * 44;   // 5632/128 interleaved n-tiles
    int nwg2 = Tc * 8;    // 1024/128 n-tiles
    for (int c = 0; c < nchunks; ++c) {
        int tile0 = c * Tc;
        gemm_m97<16, 0><<<nwg1, 256, 0, stream>>>(
            Xg, W1b, seg_off, tile_e, tile_row0, ntiles, token_id, pair_w,
            hbuf, Pbuf, out, tile0, Tc, nwg1);
        if (useP) {
            gemm_m97<44, 1><<<nwg2, 256, 0, stream>>>(
                hbuf, wd_b, seg_off, tile_e, tile_row0, ntiles, token_id, pair_w,
                hbuf, Pbuf, out, tile0, Tc, nwg2);
        } else {
            gemm_m97<44, 2><<<nwg2, 256, 0, stream>>>(
                hbuf, wd_b, seg_off, tile_e, tile_row0, ntiles, token_id, pair_w,
                hbuf, Pbuf, out, tile0, Tc, nwg2);
        }
    }
    if (useP)
        combine_kernel<<<Tt, 256, 0, stream>>>(Pbuf, pos, tok_w, out);
}

// Round 11
// 756.962 us; speedup vs baseline: 1.0548x; 1.0039x over previous
//
#include <hip/hip_runtime.h>
#include <hip/hip_bf16.h>
#include <stdint.h>

// Problem dims
#define Dd 1024
#define Ee 8
#define Ff 2816
#define Tt 8192    // B*S tokens
#define Pp 16384   // Tt * K pairs

#define BMT 128            // M tile
#define MAXT 136           // max M-tiles: Pp/128 + Ee

using bf16x8 = __attribute__((ext_vector_type(8))) short;
using f32x4  = __attribute__((ext_vector_type(4))) float;
using f4v    = __attribute__((ext_vector_type(4))) float;
using u4v    = __attribute__((ext_vector_type(4))) unsigned int;

__device__ __forceinline__ uint16_t f2bf(float f) {
    union { float f; uint32_t u; } v; v.f = f;
    return (uint16_t)((v.u + 0x7fffu + ((v.u >> 16) & 1u)) >> 16);
}
__device__ __forceinline__ uint32_t pack2(float a, float b) {
    return (uint32_t)f2bf(a) | ((uint32_t)f2bf(b) << 16);
}
__device__ __forceinline__ uint4 pack8(float4 a, float4 b) {
    uint4 r; r.x = pack2(a.x, a.y); r.y = pack2(a.z, a.w);
    r.z = pack2(b.x, b.y); r.w = pack2(b.z, b.w); return r;
}
__device__ __forceinline__ u4v pack8v(f4v a, f4v b) {
    u4v r; r.x = pack2(a.x, a.y); r.y = pack2(a.z, a.w);
    r.z = pack2(b.x, b.y); r.w = pack2(b.z, b.w); return r;
}
// XOR swizzle within a 128B LDS row (G4)
__device__ __forceinline__ int swz(int row, int cb) {
    return row * 128 + (cb ^ ((row & 7) << 4));
}
__device__ __forceinline__ void gload16(const void* g, void* lds) {
    __builtin_amdgcn_global_load_lds(
        (const __attribute__((address_space(1))) uint32_t*)(uintptr_t)g,
        (__attribute__((address_space(3))) uint32_t*)(uintptr_t)lds,
        16, 0, 0);
}
__device__ __forceinline__ int xcd_swz(int b, int nwg) {
    int xcd = b & 7, pos = b >> 3;
    int q = nwg >> 3, r = nwg & 7;
    return (xcd < r ? xcd * (q + 1) : r * (q + 1) + (xcd - r) * q) + pos;
}

// ---------------- Router ----------------
__global__ __launch_bounds__(256) void router_kernel(
    const float* __restrict__ x, const float* __restrict__ gw,
    float* __restrict__ usage_bank, int* __restrict__ counts,
    int* __restrict__ tok_i, float* __restrict__ tok_w)
{
    __shared__ float us[Ee];
    int tid = threadIdx.x;
    if (tid < Ee) us[tid] = 0.f;
    __syncthreads();
    int wave = tid >> 6, lane = tid & 63;
    int t = blockIdx.x * 4 + wave;

    float xr[16];
    const float* xp = x + (size_t)t * Dd;
    #pragma unroll
    for (int j = 0; j < 16; ++j) xr[j] = xp[lane + 64 * j];

    float logits[Ee];
    #pragma unroll
    for (int e = 0; e < Ee; ++e) {
        const float* gp = gw + e * Dd;
        float s = 0.f;
        #pragma unroll
        for (int j = 0; j < 16; ++j) s += xr[j] * gp[lane + 64 * j];
        #pragma unroll
        for (int m = 1; m < 64; m <<= 1) s += __shfl_xor(s, m, 64);
        logits[e] = s;
    }
    float v1 = -1e30f, v2 = -1e30f; int i1 = 0, i2 = 0;
    #pragma unroll
    for (int e = 0; e < Ee; ++e) {
        float l = logits[e];
        if (l > v1) { v2 = v1; i2 = i1; v1 = l; i1 = e; }
        else if (l > v2) { v2 = l; i2 = e; }
    }
    float ex2 = expf(v2 - v1);
    float w1 = 1.f / (1.f + ex2);
    float w2 = ex2 * w1;
    float p[Ee]; float se = 0.f;
    #pragma unroll
    for (int e = 0; e < Ee; ++e) { p[e] = expf(logits[e] - v1); se += p[e]; }
    float inv = 1.f / se;
    if (lane == 0) {
        #pragma unroll
        for (int e = 0; e < Ee; ++e) atomicAdd(&us[e], p[e] * inv);
        atomicAdd(&counts[i1], 1);
        atomicAdd(&counts[i2], 1);
        tok_i[t * 2] = i1; tok_i[t * 2 + 1] = i2;
        tok_w[t * 2] = w1; tok_w[t * 2 + 1] = w2;
    }
    __syncthreads();
    if (tid < Ee) atomicAdd(&usage_bank[(blockIdx.x & 63) * Ee + tid], us[tid]);
}

// ---------------- Fused weight conversion (3 ranges), nontemporal ----------------
// part 0: gate -> W1b rows (f>>4)*32+(f&15); part 1: up -> +16; part 2: wdown plain.
// Lane-contiguous 8 elems/thread; nt loads (read-once) + nt stores (no L3 pollution).
__global__ __launch_bounds__(256) void conv_fused_kernel(
    const float* __restrict__ g, const float* __restrict__ u,
    const float* __restrict__ dsrc, uint16_t* __restrict__ w1b,
    uint16_t* __restrict__ wdb)
{
    int part = blockIdx.x / 11264;
    long long i = ((long long)(blockIdx.x - part * 11264) * 256 + threadIdx.x) * 8;
    if (part == 2) {
        f4v a = __builtin_nontemporal_load((const f4v*)(dsrc + i));
        f4v b = __builtin_nontemporal_load((const f4v*)(dsrc + i + 4));
        __builtin_nontemporal_store(pack8v(a, b), (u4v*)(wdb + i));
        return;
    }
    int d = (int)(i & (Dd - 1));
    long long row = i >> 10;            // e*Ff + f
    int e = (int)(row / Ff), f = (int)(row - (long long)e * Ff);
    size_t rg = (size_t)e * 5632 + (size_t)(f >> 4) * 32 + (f & 15) + (part ? 16 : 0);
    const float* src = part ? u : g;
    f4v a = __builtin_nontemporal_load((const f4v*)(src + i));
    f4v b = __builtin_nontemporal_load((const f4v*)(src + i + 4));
    __builtin_nontemporal_store(pack8v(a, b), (u4v*)(w1b + rg * 1024 + d));
}

// ---------------- Scan: aux + offsets + tile list ----------------
__global__ void scan_kernel(const float* __restrict__ usage_bank,
                            const int* __restrict__ counts,
                            int* __restrict__ seg_off, int* __restrict__ cursor,
                            int* __restrict__ ntiles, int* __restrict__ tile_e,
                            int* __restrict__ tile_row0, float* __restrict__ out_aux)
{
    int tid = threadIdx.x;
    __shared__ float us[Ee];
    if (tid < Ee) {
        float s = 0.f;
        for (int b = 0; b < 64; ++b) s += usage_bank[b * Ee + tid];
        us[tid] = s / (float)Tt;
    }
    __syncthreads();
    if (tid == 0) {
        float aux = 0.f;
        for (int e = 0; e < Ee; ++e) { float d = us[e] - 0.125f; aux += d * d; }
        *out_aux = aux;
        int off = 0;
        for (int e = 0; e < Ee; ++e) { seg_off[e] = off; cursor[e] = off; off += counts[e]; }
        seg_off[Ee] = off;
        int ti = 0;
        for (int e = 0; e < Ee; ++e) {
            int so = seg_off[e], cnt = counts[e];
            for (int r = 0; r < cnt; r += BMT) { tile_e[ti] = e; tile_row0[ti] = so + r; ++ti; }
        }
        *ntiles = ti;   // <= MAXT
    }
}

// ---------------- Build pair lists (+ token->slot map) ----------------
__global__ __launch_bounds__(256) void build_kernel(
    const int* __restrict__ tok_i, const float* __restrict__ tok_w,
    int* __restrict__ cursor, int* __restrict__ token_id, float* __restrict__ pair_w,
    int* __restrict__ pos)
{
    int t = blockIdx.x * 256 + threadIdx.x;
    if (t >= Tt) return;
    int i1 = tok_i[t * 2], i2 = tok_i[t * 2 + 1];
    int s1 = atomicAdd(&cursor[i1], 1);
    token_id[s1] = t; pair_w[s1] = tok_w[t * 2];     pos[t * 2] = s1;
    int s2 = atomicAdd(&cursor[i2], 1);
    token_id[s2] = t; pair_w[s2] = tok_w[t * 2 + 1]; pos[t * 2 + 1] = s2;
}

// ---------------- Gather x rows -> bf16 Xg[pair, D] ----------------
__global__ __launch_bounds__(256) void gather_kernel(
    const float* __restrict__ x, const int* __restrict__ token_id,
    uint16_t* __restrict__ Xg)
{
    int wave = threadIdx.x >> 6, lane = threadIdx.x & 63;
    int r = blockIdx.x * 4 + wave;
    if (r >= Pp) return;
    int t = token_id[r];
    const float4* src = (const float4*)(x + (size_t)t * Dd) + lane * 4;
    float4 f0 = src[0], f1 = src[1], f2 = src[2], f3 = src[3];
    uint4* dst = (uint4*)(Xg + (size_t)r * Dd) + lane * 2;
    dst[0] = pack8(f0, f1);
    dst[1] = pack8(f2, f3);
}

// ---------------- m97-style GEMM: BM=128, BN=128, BK=64, 4 waves ----------------
// Single-buffered LDS (32 KB), 2-barrier loop, global_load_lds staging, 3 blocks/CU.
// Streaming outputs use nontemporal stores so L3 retains Xg/W1b/wd_b operands.
// MODE 0: gemm1 (A=Xg, B=W1b interleaved; epilogue h=silu(g)*u -> hbuf bf16, nt)
// MODE 1: gemm2 (A=hbuf, B=wd_b; epilogue P[pr] fp32 store, nt)
// MODE 2: gemm2 atomic (epilogue atomicAdd into out)
template<int NKT, int MODE>
__global__ __launch_bounds__(256, 3) void gemm_m97(
    const uint16_t* __restrict__ Abase, const uint16_t* __restrict__ Bbase,
    const int* __restrict__ seg_off, const int* __restrict__ tile_e,
    const int* __restrict__ tile_row0, const int* __restrict__ ntiles,
    const int* __restrict__ token_id, const float* __restrict__ pair_w,
    uint16_t* __restrict__ hbuf, float* __restrict__ Pbuf, float* __restrict__ out,
    int tile0, int Tc, int nwg)
{
    constexpr int LD = (MODE == 0) ? Dd : Ff;

    int wgid = xcd_swz(blockIdx.x, nwg);
    int nt = wgid / Tc, lt = wgid - nt * Tc;
    int tidx = tile0 + lt;
    if (tidx >= *ntiles) return;
    int e = tile_e[tidx];
    int row0 = tile_row0[tidx];
    int rows = seg_off[e + 1] - row0; if (rows > BMT) rows = BMT;
    int slot = lt * BMT;

    __shared__ uint4 lds4[32768 / 16];   // A 16K | B 16K
    char* smA = (char*)lds4;
    char* smB = smA + 16384;

    int tid = threadIdx.x, lane = tid & 63, wv = tid >> 6;
    int wr = wv >> 1, wc = wv & 1;

    // staging sources: per-lane inverse-swizzled (rule #21: LDS dest linear)
    int srow = wv * 32 + (lane >> 3);            // wave stages rows [wv*32, wv*32+32)
    int csw = ((lane & 7) ^ (lane >> 3)) * 8;    // source col chunk (elements)
    const uint16_t* aP;
    const uint16_t* bP;
    if constexpr (MODE == 0) {
        aP = Abase + (size_t)(row0 + srow) * LD + csw;
        bP = Bbase + ((size_t)e * 5632 + nt * 128 + srow) * LD + csw;
    } else {
        aP = Abase + (size_t)(slot + srow) * LD + csw;
        bP = Bbase + ((size_t)e * Dd + nt * 128 + srow) * LD + csw;
    }
    char* aL = smA + wv * 4096;
    char* bL = smB + wv * 4096;

    f32x4 acc[4][4];
    f32x4 zero4 = {0.f, 0.f, 0.f, 0.f};
    #pragma unroll
    for (int m = 0; m < 4; ++m)
        #pragma unroll
        for (int n = 0; n < 4; ++n) acc[m][n] = zero4;

    #pragma unroll 1
    for (int kt = 0; kt < NKT; ++kt) {
        // stage tile kt (8 gload16/wave); __syncthreads drains vmcnt+lgkm
        #pragma unroll
        for (int i = 0; i < 4; ++i) {
            gload16(aP + (size_t)(i * 8) * LD + kt * 64, aL + i * 1024);
            gload16(bP + (size_t)(i * 8) * LD + kt * 64, bL + i * 1024);
        }
        __syncthreads();
        #pragma unroll
        for (int kk = 0; kk < 2; ++kk) {
            int cb = kk * 64 + ((lane >> 4) << 4);
            bf16x8 a[4], b[4];
            #pragma unroll
            for (int m = 0; m < 4; ++m)
                a[m] = *(const bf16x8*)(smA + swz(wr * 64 + m * 16 + (lane & 15), cb));
            #pragma unroll
            for (int n = 0; n < 4; ++n)
                b[n] = *(const bf16x8*)(smB + swz(wc * 64 + n * 16 + (lane & 15), cb));
            #pragma unroll
            for (int m = 0; m < 4; ++m)
                #pragma unroll
                for (int n = 0; n < 4; ++n)
                    acc[m][n] = __builtin_amdgcn_mfma_f32_16x16x32_bf16(a[m], b[n], acc[m][n], 0, 0, 0);
        }
        __syncthreads();   // all waves done reading before next stage overwrites
    }

    if constexpr (MODE == 0) {
        // interleaved n-frags: (0,1)=(g,u) at f0, (2,3)=(g,u) at f0+16
        int hc = nt * 64 + wc * 32 + (lane & 15);
        #pragma unroll
        for (int m = 0; m < 4; ++m) {
            #pragma unroll
            for (int g = 0; g < 4; ++g) {
                int rr = wr * 64 + m * 16 + (lane >> 4) * 4 + g;
                if (rr < rows) {
                    uint16_t* hp = hbuf + (size_t)(slot + rr) * Ff + hc;
                    float g0 = acc[m][0][g], u0 = acc[m][1][g];
                    __builtin_nontemporal_store(f2bf(g0 * u0 / (1.f + expf(-g0))), hp);
                    float g1 = acc[m][2][g], u1 = acc[m][3][g];
                    __builtin_nontemporal_store(f2bf(g1 * u1 / (1.f + expf(-g1))), hp + 16);
                }
            }
        }
    } else if constexpr (MODE == 1) {
        int col = nt * 128 + wc * 64 + (lane & 15);
        #pragma unroll
        for (int m = 0; m < 4; ++m) {
            #pragma unroll
            for (int g = 0; g < 4; ++g) {
                int rr = wr * 64 + m * 16 + (lane >> 4) * 4 + g;
                if (rr < rows) {
                    float* pp = Pbuf + (size_t)(row0 + rr) * Dd + col;
                    __builtin_nontemporal_store(acc[m][0][g], pp);
                    __builtin_nontemporal_store(acc[m][1][g], pp + 16);
                    __builtin_nontemporal_store(acc[m][2][g], pp + 32);
                    __builtin_nontemporal_store(acc[m][3][g], pp + 48);
                }
            }
        }
    } else {
        int col = nt * 128 + wc * 64 + (lane & 15);
        #pragma unroll
        for (int m = 0; m < 4; ++m) {
            #pragma unroll
            for (int g = 0; g < 4; ++g) {
                int rr = wr * 64 + m * 16 + (lane >> 4) * 4 + g;
                if (rr < rows) {
                    int pr = row0 + rr;
                    int tok = token_id[pr];
                    float w = pair_w[pr];
                    float* op = out + (size_t)tok * Dd + col;
                    atomicAdd(op + 0,  w * acc[m][0][g]);
                    atomicAdd(op + 16, w * acc[m][1][g]);
                    atomicAdd(op + 32, w * acc[m][2][g]);
                    atomicAdd(op + 48, w * acc[m][3][g]);
                }
            }
        }
    }
}

// ---------------- Combine: out[t] = w1*P[s1] + w2*P[s2] ----------------
__global__ __launch_bounds__(256) void combine_kernel(
    const float* __restrict__ P, const int* __restrict__ pos,
    const float* __restrict__ tok_w, float* __restrict__ out)
{
    int t = blockIdx.x;
    int d = threadIdx.x * 4;
    int s1 = pos[t * 2], s2 = pos[t * 2 + 1];
    float w1 = tok_w[t * 2], w2 = tok_w[t * 2 + 1];
    f4v a = __builtin_nontemporal_load((const f4v*)(P + (size_t)s1 * Dd + d));
    f4v b = __builtin_nontemporal_load((const f4v*)(P + (size_t)s2 * Dd + d));
    f4v o = w1 * a + w2 * b;
    *(f4v*)(out + (size_t)t * Dd + d) = o;
}

// ---------------- Host launch ----------------
extern "C" void kernel_launch(void* const* d_in, const int* in_sizes, int n_in,
                              void* d_out, int out_size, void* d_ws, size_t ws_size,
                              hipStream_t stream)
{
    const float* x     = (const float*)d_in[0];
    const float* gw    = (const float*)d_in[1];
    const float* wgate = (const float*)d_in[2];
    const float* wup   = (const float*)d_in[3];
    const float* wdown = (const float*)d_in[4];
    float* out = (float*)d_out;

    char* ws = (char*)d_ws;
    float* usage_bank = (float*)(ws);
    int*   counts     = (int*)(ws + 2048);
    int*   seg_off    = (int*)(ws + 2112);
    int*   cursor     = (int*)(ws + 2176);
    int*   ntiles     = (int*)(ws + 2240);
    int*   tile_e     = (int*)(ws + 4096);
    int*   tile_row0  = (int*)(ws + 5120);
    int*   tok_i      = (int*)(ws + 8192);
    float* tok_w      = (float*)(ws + 73728);
    int*   token_id   = (int*)(ws + 139264);
    float* pair_w     = (float*)(ws + 204800);
    int*   pos        = (int*)(ws + 270336);
    const size_t CTRL  = 335872;
    const size_t TILEB = (size_t)BMT * Ff * 2;          // 720,896 B per h-tile
    const size_t XgB   = (size_t)(Pp + BMT) * Dd * 2;   // 33.8 MB (padded)
    const size_t W1B   = 2ull * Ee * Ff * Dd * 2;       // 92.3 MB interleaved gate/up
    const size_t WDB   = (size_t)Ee * Dd * Ff * 2;      // 46.1 MB
    const size_t PB    = (size_t)Pp * Dd * 4;           // 67.1 MB fp32 per-pair rows

    if (ws_size >= 4096) hipMemsetAsync(ws, 0, 4096, stream);
    size_t fixed = CTRL + XgB + W1B + WDB;
    if (ws_size < fixed + TILEB) {   // cannot run the fast path; fail gracefully (no OOB)
        hipMemsetAsync(d_out, 0, (size_t)out_size * 4, stream);
        return;
    }

    uint16_t* Xg   = (uint16_t*)(ws + CTRL);
    uint16_t* W1b  = (uint16_t*)(ws + CTRL + XgB);
    uint16_t* wd_b = (uint16_t*)(ws + CTRL + XgB + W1B);
    size_t rem = ws_size - fixed;

    router_kernel<<<Tt / 4, 256, 0, stream>>>(x, gw, usage_bank, counts, tok_i, tok_w);
    scan_kernel<<<1, 64, 0, stream>>>(usage_bank, counts, seg_off, cursor,
                                      ntiles, tile_e, tile_row0, out + (out_size - 1));
    build_kernel<<<Tt / 256, 256, 0, stream>>>(tok_i, tok_w, cursor, token_id, pair_w, pos);
    gather_kernel<<<Pp / 4, 256, 0, stream>>>(x, token_id, Xg);
    conv_fused_kernel<<<33792, 256, 0, stream>>>(wgate, wup, wdown, W1b, wd_b);

    // choose P-buffer mode (store + combine) vs atomic mode
    int TcP = (rem > PB) ? (int)((rem - PB) / TILEB) : 0;
    if (TcP > MAXT) TcP = MAXT;
    bool useP = (TcP >= 24);
    float* Pbuf = nullptr;
    uint16_t* hbuf;
    int Tc;
    if (useP) {
        Pbuf = (float*)(ws + fixed);
        hbuf = (uint16_t*)(ws + fixed + PB);
        Tc = TcP;
    } else {
        hbuf = (uint16_t*)(ws + fixed);
        Tc = (int)(rem / TILEB);
        if (Tc > MAXT) Tc = MAXT;
        hipMemsetAsync(d_out, 0, (size_t)(out_size - 1) * 4, stream);  // atomics need zeroed out
    }
    int nchunks = (MAXT + Tc - 1) / Tc;
    Tc = (MAXT + nchunks - 1) / nchunks;   // even split

    int nwg1 = Tc * 44;   // 5632/128 interleaved n-tiles
    int nwg2 = Tc * 8;    // 1024/128 n-tiles
    for (int c = 0; c < nchunks; ++c) {
        int tile0 = c * Tc;
        gemm_m97<16, 0><<<nwg1, 256, 0, stream>>>(
            Xg, W1b, seg_off, tile_e, tile_row0, ntiles, token_id, pair_w,
            hbuf, Pbuf, out, tile0, Tc, nwg1);
        if (useP) {
            gemm_m97<44, 1><<<nwg2, 256, 0, stream>>>(
                hbuf, wd_b, seg_off, tile_e, tile_row0, ntiles, token_id, pair_w,
                hbuf, Pbuf, out, tile0, Tc, nwg2);
        } else {
            gemm_m97<44, 2><<<nwg2, 256, 0, stream>>>(
                hbuf, wd_b, seg_off, tile_e, tile_row0, ntiles, token_id, pair_w,
                hbuf, Pbuf, out, tile0, Tc, nwg2);
        }
    }
    if (useP)
        combine_kernel<<<Tt, 256, 0, stream>>>(Pbuf, pos, tok_w, out);
}